// Round 3
// baseline (3677.768 us; speedup 1.0000x reference)
//
#include <hip/hip_runtime.h>

#define NCH 16
#define DIRR 9

// ======================= compile-time Clebsch-Gordan =======================
namespace cg {

struct CD { double re, im; };

constexpr CD conjc(CD a){ return CD{a.re, -a.im}; }
constexpr CD cmul(CD a, CD b){ return CD{a.re*b.re - a.im*b.im, a.re*b.im + a.im*b.re}; }

constexpr double cfact(int n){ double r = 1.0; for (int i = 2; i <= n; i++) r *= (double)i; return r; }
constexpr double cabsd(double x){ return x < 0 ? -x : x; }

constexpr double csqrt(double x){
  if (x <= 0.0) return 0.0;
  double g = x > 1.0 ? x : 1.0;
  double prev = 0.0;
  for (int i = 0; i < 100; i++){
    if (g == prev) break;
    prev = g;
    g = 0.5 * (g + x / g);
  }
  return g;
}

struct CG3 { double v[5][5][5]; };

// Complex Clebsch-Gordan <j1 m1 j2 m2 | j3 m3> (Racah formula)
constexpr CG3 cg_complex(int j1, int j2, int j3){
  CG3 C{};
  if (j1 + j2 - j3 < 0 || j1 - j2 + j3 < 0 || -j1 + j2 + j3 < 0) return C;
  double pref0 = csqrt((2*j3+1) * cfact(j1+j2-j3) * cfact(j1-j2+j3) * cfact(-j1+j2+j3)
                       / cfact(j1+j2+j3+1));
  for (int m1 = -j1; m1 <= j1; m1++){
    for (int m2 = -j2; m2 <= j2; m2++){
      int m3 = m1 + m2;
      if (m3 < -j3 || m3 > j3) continue;
      double pref = pref0 * csqrt(cfact(j1+m1)*cfact(j1-m1)*cfact(j2+m2)*cfact(j2-m2)
                                  *cfact(j3+m3)*cfact(j3-m3));
      double s = 0.0;
      for (int k = 0; k <= j1 + j2 - j3; k++){
        int d1 = j1 + j2 - j3 - k;
        int d2 = j1 - m1 - k;
        int d3 = j2 + m2 - k;
        int d4 = j3 - j2 + m1 + k;
        int d5 = j3 - j1 - m2 + k;
        if (d1 < 0 || d2 < 0 || d3 < 0 || d4 < 0 || d5 < 0) continue;
        double denom = cfact(k)*cfact(d1)*cfact(d2)*cfact(d3)*cfact(d4)*cfact(d5);
        s += ((k & 1) ? -1.0 : 1.0) / denom;
      }
      C.v[m1+j1][m2+j2][m3+j3] = pref * s;
    }
  }
  return C;
}

struct CM { CD a[5][5]; };

// Unitary change of basis complex->real spherical harmonics
constexpr CM real_mat(int l){
  CM A{};
  A.a[l][l] = CD{1.0, 0.0};
  double s = 1.0 / csqrt(2.0);
  for (int m = 1; m <= l; m++){
    double sgn = (m & 1) ? -1.0 : 1.0;
    A.a[l+m][l+m] = CD{sgn * s, 0.0};
    A.a[l+m][l-m] = CD{s, 0.0};
    A.a[l-m][l-m] = CD{0.0, s};
    A.a[l-m][l+m] = CD{0.0, -sgn * s};
  }
  return A;
}

struct RCG { float v[5][5][5]; };

constexpr RCG real_cg(int l1, int l2, int l3){
  CG3 C = cg_complex(l1, l2, l3);
  CM A1 = real_mat(l1), A2 = real_mat(l2), A3 = real_mat(l3);
  int n1 = 2*l1 + 1, n2 = 2*l2 + 1, n3 = 2*l3 + 1;
  double re[5][5][5]{}, im[5][5][5]{};
  double maxre = 0.0, maxim = 0.0;
  for (int a = 0; a < n1; a++)
    for (int b = 0; b < n2; b++)
      for (int c = 0; c < n3; c++){
        double sre = 0.0, sim = 0.0;
        // A[row][col] nonzero only for col in {row, 2l-row} -> enumerate candidates
        int mc0 = a, mc1 = 2*l1 - a; int nm = (mc0 == mc1) ? 1 : 2;
        int nc0 = b, nc1 = 2*l2 - b; int nn = (nc0 == nc1) ? 1 : 2;
        int oc0 = c, oc1 = 2*l3 - c; int no = (oc0 == oc1) ? 1 : 2;
        for (int mi = 0; mi < nm; mi++)
          for (int ni = 0; ni < nn; ni++)
            for (int oi = 0; oi < no; oi++){
              int m = mi ? mc1 : mc0;
              int n = ni ? nc1 : nc0;
              int o = oi ? oc1 : oc0;
              double cv = C.v[m][n][o];
              if (cv == 0.0) continue;
              CD p = cmul(cmul(conjc(A1.a[a][m]), conjc(A2.a[b][n])), A3.a[c][o]);
              sre += p.re * cv;
              sim += p.im * cv;
            }
        re[a][b][c] = sre; im[a][b][c] = sim;
        if (cabsd(sre) > maxre) maxre = cabsd(sre);
        if (cabsd(sim) > maxim) maxim = cabsd(sim);
      }
  RCG R{};
  bool useRe = (maxre >= maxim);
  for (int a = 0; a < n1; a++)
    for (int b = 0; b < n2; b++)
      for (int c = 0; c < n3; c++)
        R.v[a][b][c] = (float)(useRe ? re[a][b][c] : im[a][b][c]);
  return R;
}

constexpr int imin_(int a, int b){ return a < b ? a : b; }
constexpr int iabs_(int a){ return a < 0 ? -a : a; }

struct TPW { float w[9][9][9]; };

constexpr TPW tp_tensor(){
  TPW W{};
  for (int l1 = 0; l1 <= 2; l1++)
    for (int l2 = 0; l2 <= 2; l2++)
      for (int l3 = iabs_(l1 - l2); l3 <= imin_(l1 + l2, 2); l3++){
        RCG R = real_cg(l1, l2, l3);
        for (int a = 0; a < 2*l1 + 1; a++)
          for (int b = 0; b < 2*l2 + 1; b++)
            for (int c = 0; c < 2*l3 + 1; c++)
              W.w[l1*l1 + a][l2*l2 + b][l3*l3 + c] += R.v[a][b][c];
      }
  return W;
}

constexpr TPW TPWC = tp_tensor();
constexpr RCG CG112 = real_cg(1, 1, 2);

} // namespace cg

// ======================= kernels =======================

// One thread per (edge, channel). Computes sh (redundant x16 per edge),
// sparse CG contraction fully unrolled with compile-time constants,
// then 9 atomicAdds into the aggregation buffer (= d_out).
__global__ __launch_bounds__(256) void edge_scatter(
    const float* __restrict__ pos,
    const float* __restrict__ nf,
    const int*   __restrict__ snd,
    const int*   __restrict__ rcv,
    float*       __restrict__ out,
    int n_edges)
{
  int t = blockIdx.x * 256 + threadIdx.x;
  int e = t >> 4;
  if (e >= n_edges) return;
  int c = t & 15;

  int s = snd[e];
  int r = rcv[e];

  float dx = pos[3*r + 0] - pos[3*s + 0];
  float dy = pos[3*r + 1] - pos[3*s + 1];
  float dz = pos[3*r + 2] - pos[3*s + 2];
  float inv = rsqrtf(dx*dx + dy*dy + dz*dz + 1e-12f);

  // y1 = normalized r permuted [1,2,0] -> (y, z, x)
  float y1[3] = { dy*inv, dz*inv, dx*inv };

  float sh[9];
  sh[0] = 1.0f; sh[1] = y1[0]; sh[2] = y1[1]; sh[3] = y1[2];

  float y2[5] = {0.f, 0.f, 0.f, 0.f, 0.f};
#pragma unroll
  for (int a = 0; a < 3; a++)
#pragma unroll
    for (int b = 0; b < 3; b++)
#pragma unroll
      for (int k = 0; k < 5; k++)
        if (cg::CG112.v[a][b][k] != 0.0f)
          y2[k] += y1[a] * y1[b] * cg::CG112.v[a][b][k];

  float n2 = y2[0]*y2[0] + y2[1]*y2[1] + y2[2]*y2[2] + y2[3]*y2[3] + y2[4]*y2[4] + 1e-12f;
  float invy = rsqrtf(n2);
#pragma unroll
  for (int k = 0; k < 5; k++) sh[4 + k] = y2[k] * invy;

  const float* xp = nf + ((size_t)s * NCH + c) * DIRR;
  float x[9];
#pragma unroll
  for (int i = 0; i < 9; i++) x[i] = xp[i];

  float acc[9] = {0.f,0.f,0.f,0.f,0.f,0.f,0.f,0.f,0.f};
#pragma unroll
  for (int i = 0; i < 9; i++){
#pragma unroll
    for (int j = 0; j < 9; j++){
#pragma unroll
      for (int k = 0; k < 9; k++){
        if (cg::TPWC.w[i][j][k] != 0.0f)
          acc[k] += (x[i] * sh[j]) * cg::TPWC.w[i][j][k];
      }
    }
  }

  float* o = out + ((size_t)r * NCH + c) * DIRR;
#pragma unroll
  for (int k = 0; k < 9; k++) atomicAdd(o + k, acc[k]);
}

// In-place per-row dense: row[0:9] = row[0:9] @ dense_w + b. Rows independent.
__global__ __launch_bounds__(256) void dense_inplace(
    const float* __restrict__ dw,
    const float* __restrict__ db,
    float*       __restrict__ out,
    int n_rows)
{
  int t = blockIdx.x * 256 + threadIdx.x;
  if (t >= n_rows) return;
  float* row = out + (size_t)t * DIRR;
  float x[9];
#pragma unroll
  for (int i = 0; i < 9; i++) x[i] = row[i];
#pragma unroll
  for (int k = 0; k < 9; k++){
    float v = db[k];
#pragma unroll
    for (int i = 0; i < 9; i++) v += x[i] * dw[i*9 + k];
    row[k] = v;
  }
}

extern "C" void kernel_launch(void* const* d_in, const int* in_sizes, int n_in,
                              void* d_out, int out_size, void* d_ws, size_t ws_size,
                              hipStream_t stream)
{
  const float* pos = (const float*)d_in[0];
  const float* nf  = (const float*)d_in[1];
  const float* dw  = (const float*)d_in[2];
  const float* db  = (const float*)d_in[3];
  const int*   snd = (const int*)d_in[4];
  const int*   rcv = (const int*)d_in[5];
  float* out = (float*)d_out;

  int n_edges = in_sizes[4];
  int n_nodes = in_sizes[0] / 3;

  // d_out doubles as the segment-sum accumulator; zero it first.
  hipMemsetAsync(out, 0, (size_t)out_size * sizeof(float), stream);

  int threads = n_edges * NCH;
  edge_scatter<<<dim3((threads + 255) / 256), dim3(256), 0, stream>>>(
      pos, nf, snd, rcv, out, n_edges);

  int rows = n_nodes * NCH;
  dense_inplace<<<dim3((rows + 255) / 256), dim3(256), 0, stream>>>(
      dw, db, out, rows);
}

// Round 4
// 373.291 us; speedup vs baseline: 9.8523x; 9.8523x over previous
//
#include <hip/hip_runtime.h>

#define NCH 16
#define DIRR 9

// ======================= compile-time Clebsch-Gordan =======================
namespace cg {

struct CD { double re, im; };

constexpr CD conjc(CD a){ return CD{a.re, -a.im}; }
constexpr CD cmul(CD a, CD b){ return CD{a.re*b.re - a.im*b.im, a.re*b.im + a.im*b.re}; }

constexpr double cfact(int n){ double r = 1.0; for (int i = 2; i <= n; i++) r *= (double)i; return r; }
constexpr double cabsd(double x){ return x < 0 ? -x : x; }

constexpr double csqrt(double x){
  if (x <= 0.0) return 0.0;
  double g = x > 1.0 ? x : 1.0;
  double prev = 0.0;
  for (int i = 0; i < 100; i++){
    if (g == prev) break;
    prev = g;
    g = 0.5 * (g + x / g);
  }
  return g;
}

struct CG3 { double v[5][5][5]; };

// Complex Clebsch-Gordan <j1 m1 j2 m2 | j3 m3> (Racah formula)
constexpr CG3 cg_complex(int j1, int j2, int j3){
  CG3 C{};
  if (j1 + j2 - j3 < 0 || j1 - j2 + j3 < 0 || -j1 + j2 + j3 < 0) return C;
  double pref0 = csqrt((2*j3+1) * cfact(j1+j2-j3) * cfact(j1-j2+j3) * cfact(-j1+j2+j3)
                       / cfact(j1+j2+j3+1));
  for (int m1 = -j1; m1 <= j1; m1++){
    for (int m2 = -j2; m2 <= j2; m2++){
      int m3 = m1 + m2;
      if (m3 < -j3 || m3 > j3) continue;
      double pref = pref0 * csqrt(cfact(j1+m1)*cfact(j1-m1)*cfact(j2+m2)*cfact(j2-m2)
                                  *cfact(j3+m3)*cfact(j3-m3));
      double s = 0.0;
      for (int k = 0; k <= j1 + j2 - j3; k++){
        int d1 = j1 + j2 - j3 - k;
        int d2 = j1 - m1 - k;
        int d3 = j2 + m2 - k;
        int d4 = j3 - j2 + m1 + k;
        int d5 = j3 - j1 - m2 + k;
        if (d1 < 0 || d2 < 0 || d3 < 0 || d4 < 0 || d5 < 0) continue;
        double denom = cfact(k)*cfact(d1)*cfact(d2)*cfact(d3)*cfact(d4)*cfact(d5);
        s += ((k & 1) ? -1.0 : 1.0) / denom;
      }
      C.v[m1+j1][m2+j2][m3+j3] = pref * s;
    }
  }
  return C;
}

struct CM { CD a[5][5]; };

// Unitary change of basis complex->real spherical harmonics
constexpr CM real_mat(int l){
  CM A{};
  A.a[l][l] = CD{1.0, 0.0};
  double s = 1.0 / csqrt(2.0);
  for (int m = 1; m <= l; m++){
    double sgn = (m & 1) ? -1.0 : 1.0;
    A.a[l+m][l+m] = CD{sgn * s, 0.0};
    A.a[l+m][l-m] = CD{s, 0.0};
    A.a[l-m][l-m] = CD{0.0, s};
    A.a[l-m][l+m] = CD{0.0, -sgn * s};
  }
  return A;
}

struct RCG { float v[5][5][5]; };

constexpr RCG real_cg(int l1, int l2, int l3){
  CG3 C = cg_complex(l1, l2, l3);
  CM A1 = real_mat(l1), A2 = real_mat(l2), A3 = real_mat(l3);
  int n1 = 2*l1 + 1, n2 = 2*l2 + 1, n3 = 2*l3 + 1;
  double re[5][5][5]{}, im[5][5][5]{};
  double maxre = 0.0, maxim = 0.0;
  for (int a = 0; a < n1; a++)
    for (int b = 0; b < n2; b++)
      for (int c = 0; c < n3; c++){
        double sre = 0.0, sim = 0.0;
        int mc0 = a, mc1 = 2*l1 - a; int nm = (mc0 == mc1) ? 1 : 2;
        int nc0 = b, nc1 = 2*l2 - b; int nn = (nc0 == nc1) ? 1 : 2;
        int oc0 = c, oc1 = 2*l3 - c; int no = (oc0 == oc1) ? 1 : 2;
        for (int mi = 0; mi < nm; mi++)
          for (int ni = 0; ni < nn; ni++)
            for (int oi = 0; oi < no; oi++){
              int m = mi ? mc1 : mc0;
              int n = ni ? nc1 : nc0;
              int o = oi ? oc1 : oc0;
              double cv = C.v[m][n][o];
              if (cv == 0.0) continue;
              CD p = cmul(cmul(conjc(A1.a[a][m]), conjc(A2.a[b][n])), A3.a[c][o]);
              sre += p.re * cv;
              sim += p.im * cv;
            }
        re[a][b][c] = sre; im[a][b][c] = sim;
        if (cabsd(sre) > maxre) maxre = cabsd(sre);
        if (cabsd(sim) > maxim) maxim = cabsd(sim);
      }
  RCG R{};
  bool useRe = (maxre >= maxim);
  for (int a = 0; a < n1; a++)
    for (int b = 0; b < n2; b++)
      for (int c = 0; c < n3; c++)
        R.v[a][b][c] = (float)(useRe ? re[a][b][c] : im[a][b][c]);
  return R;
}

constexpr int imin_(int a, int b){ return a < b ? a : b; }
constexpr int iabs_(int a){ return a < 0 ? -a : a; }

struct TPW { float w[9][9][9]; };

constexpr TPW tp_tensor(){
  TPW W{};
  for (int l1 = 0; l1 <= 2; l1++)
    for (int l2 = 0; l2 <= 2; l2++)
      for (int l3 = iabs_(l1 - l2); l3 <= imin_(l1 + l2, 2); l3++){
        RCG R = real_cg(l1, l2, l3);
        for (int a = 0; a < 2*l1 + 1; a++)
          for (int b = 0; b < 2*l2 + 1; b++)
            for (int c = 0; c < 2*l3 + 1; c++)
              W.w[l1*l1 + a][l2*l2 + b][l3*l3 + c] += R.v[a][b][c];
      }
  return W;
}

constexpr TPW TPWC = tp_tensor();
constexpr RCG CG112 = real_cg(1, 1, 2);

} // namespace cg

// ======================= CSR build kernels =======================

// counts[r]++ per edge. counts array is small (200KB) -> atomics stay in L2.
__global__ __launch_bounds__(256) void hist_kernel(
    const int* __restrict__ rcv, int* __restrict__ counts, int n_edges)
{
  int e = blockIdx.x * 256 + threadIdx.x;
  if (e < n_edges) atomicAdd(&counts[rcv[e]], 1);
}

// Single-block exclusive scan: counts[0..n) -> offs[0..n], offs[n]=total.
// 1024 threads = 16 waves; shfl-based wave scan, 3 barriers per 1024-chunk.
__global__ __launch_bounds__(1024) void scan_kernel(
    const int* __restrict__ counts, int* __restrict__ offs, int n)
{
  const int tid = threadIdx.x;
  const int lane = tid & 63, wv = tid >> 6;
  __shared__ int wsum[16];
  __shared__ int running;
  if (tid == 0) running = 0;
  __syncthreads();
  for (int base = 0; base < n; base += 1024){
    int i = base + tid;
    int v = (i < n) ? counts[i] : 0;
    int x = v;
#pragma unroll
    for (int d = 1; d < 64; d <<= 1){
      int y = __shfl_up(x, d, 64);
      if (lane >= d) x += y;
    }
    if (lane == 63) wsum[wv] = x;
    __syncthreads();
    if (wv == 0 && lane < 16){
      int s = wsum[lane];
      int xs = s;
#pragma unroll
      for (int d = 1; d < 16; d <<= 1){
        int y = __shfl_up(xs, d, 16);
        if (lane >= d) xs += y;
      }
      wsum[lane] = xs - s;  // exclusive prefix of wave sums
    }
    __syncthreads();
    int excl = running + wsum[wv] + (x - v);
    if (i < n) offs[i] = excl;
    __syncthreads();  // everyone reads `running` before update
    if (tid == 1023) running += wsum[15] + x;  // chunk total
    __syncthreads();
  }
  if (tid == 0) offs[n] = running;
}

// cursor[i] = offs[i]
__global__ __launch_bounds__(256) void copy_kernel(
    const int* __restrict__ offs, int* __restrict__ cursor, int n)
{
  int i = blockIdx.x * 256 + threadIdx.x;
  if (i < n) cursor[i] = offs[i];
}

// Scatter sender ids into receiver-sorted order.
__global__ __launch_bounds__(256) void fill_kernel(
    const int* __restrict__ snd, const int* __restrict__ rcv,
    int* __restrict__ cursor, int* __restrict__ sorted, int n_edges)
{
  int e = blockIdx.x * 256 + threadIdx.x;
  if (e >= n_edges) return;
  int p = atomicAdd(&cursor[rcv[e]], 1);
  sorted[p] = snd[e];
}

// ======================= gather + fused dense =======================
// One thread per (node, channel). Walks the node's CSR edge list, computes
// sh per edge (16x redundant across channels), accumulates the 9-dim message
// in registers, applies dense_w/dense_b in-register, one 36B store. No atomics.
__global__ __launch_bounds__(256) void gather_nodes(
    const float* __restrict__ pos,
    const float* __restrict__ nf,
    const float* __restrict__ dw,
    const float* __restrict__ db,
    const int*   __restrict__ offs,
    const int*   __restrict__ sorted,
    float*       __restrict__ out,
    int n_nodes)
{
  int t = blockIdx.x * 256 + threadIdx.x;
  int n = t >> 4;
  if (n >= n_nodes) return;
  int c = t & 15;

  float prx = pos[3*n + 0], pry = pos[3*n + 1], prz = pos[3*n + 2];
  int b0 = offs[n], b1 = offs[n + 1];

  float agg[9] = {0.f,0.f,0.f,0.f,0.f,0.f,0.f,0.f,0.f};

  for (int idx = b0; idx < b1; idx++){
    int s = sorted[idx];

    float dx = prx - pos[3*s + 0];
    float dy = pry - pos[3*s + 1];
    float dz = prz - pos[3*s + 2];
    float inv = rsqrtf(dx*dx + dy*dy + dz*dz + 1e-12f);

    float y1[3] = { dy*inv, dz*inv, dx*inv };  // (y,z,x)

    float sh[9];
    sh[0] = 1.0f; sh[1] = y1[0]; sh[2] = y1[1]; sh[3] = y1[2];

    float y2[5] = {0.f,0.f,0.f,0.f,0.f};
#pragma unroll
    for (int a = 0; a < 3; a++)
#pragma unroll
      for (int b = 0; b < 3; b++)
#pragma unroll
        for (int k = 0; k < 5; k++)
          if (cg::CG112.v[a][b][k] != 0.0f)
            y2[k] += y1[a] * y1[b] * cg::CG112.v[a][b][k];

    float n2 = y2[0]*y2[0] + y2[1]*y2[1] + y2[2]*y2[2] + y2[3]*y2[3] + y2[4]*y2[4] + 1e-12f;
    float invy = rsqrtf(n2);
#pragma unroll
    for (int k = 0; k < 5; k++) sh[4 + k] = y2[k] * invy;

    const float* xp = nf + ((size_t)s * NCH + c) * DIRR;
    float x[9];
#pragma unroll
    for (int i = 0; i < 9; i++) x[i] = xp[i];

#pragma unroll
    for (int i = 0; i < 9; i++){
#pragma unroll
      for (int j = 0; j < 9; j++){
#pragma unroll
        for (int k = 0; k < 9; k++){
          if (cg::TPWC.w[i][j][k] != 0.0f)
            agg[k] += (x[i] * sh[j]) * cg::TPWC.w[i][j][k];
        }
      }
    }
  }

  // fused dense: o = agg @ dw + db
  float* op = out + ((size_t)n * NCH + c) * DIRR;
#pragma unroll
  for (int k = 0; k < 9; k++){
    float v = db[k];
#pragma unroll
    for (int i = 0; i < 9; i++) v += agg[i] * dw[i*9 + k];
    op[k] = v;
  }
}

extern "C" void kernel_launch(void* const* d_in, const int* in_sizes, int n_in,
                              void* d_out, int out_size, void* d_ws, size_t ws_size,
                              hipStream_t stream)
{
  const float* pos = (const float*)d_in[0];
  const float* nf  = (const float*)d_in[1];
  const float* dw  = (const float*)d_in[2];
  const float* db  = (const float*)d_in[3];
  const int*   snd = (const int*)d_in[4];
  const int*   rcv = (const int*)d_in[5];
  float* out = (float*)d_out;

  int n_edges = in_sizes[4];
  int n_nodes = in_sizes[0] / 3;

  // ws layout (ints): offs[n_nodes+1] | cursor/counts[n_nodes] | sorted[n_edges]
  int* offs   = (int*)d_ws;
  int* cursor = offs + (n_nodes + 1);
  int* sorted = cursor + n_nodes;

  // counts (=cursor array) must be zero each call (ws is re-poisoned to 0xAA).
  hipMemsetAsync(cursor, 0, (size_t)n_nodes * sizeof(int), stream);

  hist_kernel<<<dim3((n_edges + 255) / 256), dim3(256), 0, stream>>>(rcv, cursor, n_edges);
  scan_kernel<<<dim3(1), dim3(1024), 0, stream>>>(cursor, offs, n_nodes);
  copy_kernel<<<dim3((n_nodes + 255) / 256), dim3(256), 0, stream>>>(offs, cursor, n_nodes);
  fill_kernel<<<dim3((n_edges + 255) / 256), dim3(256), 0, stream>>>(snd, rcv, cursor, sorted, n_edges);

  int threads = n_nodes * NCH;
  gather_nodes<<<dim3((threads + 255) / 256), dim3(256), 0, stream>>>(
      pos, nf, dw, db, offs, sorted, out, n_nodes);
}

// Round 8
// 297.737 us; speedup vs baseline: 12.3524x; 1.2538x over previous
//
#include <hip/hip_runtime.h>

#define NCH 16
#define DIRR 9

// ======================= compile-time Clebsch-Gordan =======================
namespace cg {

struct CD { double re, im; };

constexpr CD conjc(CD a){ return CD{a.re, -a.im}; }
constexpr CD cmul(CD a, CD b){ return CD{a.re*b.re - a.im*b.im, a.re*b.im + a.im*b.re}; }

constexpr double cfact(int n){ double r = 1.0; for (int i = 2; i <= n; i++) r *= (double)i; return r; }
constexpr double cabsd(double x){ return x < 0 ? -x : x; }

constexpr double csqrt(double x){
  if (x <= 0.0) return 0.0;
  double g = x > 1.0 ? x : 1.0;
  double prev = 0.0;
  for (int i = 0; i < 100; i++){
    if (g == prev) break;
    prev = g;
    g = 0.5 * (g + x / g);
  }
  return g;
}

struct CG3 { double v[5][5][5]; };

// Complex Clebsch-Gordan <j1 m1 j2 m2 | j3 m3> (Racah formula)
constexpr CG3 cg_complex(int j1, int j2, int j3){
  CG3 C{};
  if (j1 + j2 - j3 < 0 || j1 - j2 + j3 < 0 || -j1 + j2 + j3 < 0) return C;
  double pref0 = csqrt((2*j3+1) * cfact(j1+j2-j3) * cfact(j1-j2+j3) * cfact(-j1+j2+j3)
                       / cfact(j1+j2+j3+1));
  for (int m1 = -j1; m1 <= j1; m1++){
    for (int m2 = -j2; m2 <= j2; m2++){
      int m3 = m1 + m2;
      if (m3 < -j3 || m3 > j3) continue;
      double pref = pref0 * csqrt(cfact(j1+m1)*cfact(j1-m1)*cfact(j2+m2)*cfact(j2-m2)
                                  *cfact(j3+m3)*cfact(j3-m3));
      double s = 0.0;
      for (int k = 0; k <= j1 + j2 - j3; k++){
        int d1 = j1 + j2 - j3 - k;
        int d2 = j1 - m1 - k;
        int d3 = j2 + m2 - k;
        int d4 = j3 - j2 + m1 + k;
        int d5 = j3 - j1 - m2 + k;
        if (d1 < 0 || d2 < 0 || d3 < 0 || d4 < 0 || d5 < 0) continue;
        double denom = cfact(k)*cfact(d1)*cfact(d2)*cfact(d3)*cfact(d4)*cfact(d5);
        s += ((k & 1) ? -1.0 : 1.0) / denom;
      }
      C.v[m1+j1][m2+j2][m3+j3] = pref * s;
    }
  }
  return C;
}

struct CM { CD a[5][5]; };

// Unitary change of basis complex->real spherical harmonics
constexpr CM real_mat(int l){
  CM A{};
  A.a[l][l] = CD{1.0, 0.0};
  double s = 1.0 / csqrt(2.0);
  for (int m = 1; m <= l; m++){
    double sgn = (m & 1) ? -1.0 : 1.0;
    A.a[l+m][l+m] = CD{sgn * s, 0.0};
    A.a[l+m][l-m] = CD{s, 0.0};
    A.a[l-m][l-m] = CD{0.0, s};
    A.a[l-m][l+m] = CD{0.0, -sgn * s};
  }
  return A;
}

struct RCG { float v[5][5][5]; };

constexpr RCG real_cg(int l1, int l2, int l3){
  CG3 C = cg_complex(l1, l2, l3);
  CM A1 = real_mat(l1), A2 = real_mat(l2), A3 = real_mat(l3);
  int n1 = 2*l1 + 1, n2 = 2*l2 + 1, n3 = 2*l3 + 1;
  double re[5][5][5]{}, im[5][5][5]{};
  double maxre = 0.0, maxim = 0.0;
  for (int a = 0; a < n1; a++)
    for (int b = 0; b < n2; b++)
      for (int c = 0; c < n3; c++){
        double sre = 0.0, sim = 0.0;
        int mc0 = a, mc1 = 2*l1 - a; int nm = (mc0 == mc1) ? 1 : 2;
        int nc0 = b, nc1 = 2*l2 - b; int nn = (nc0 == nc1) ? 1 : 2;
        int oc0 = c, oc1 = 2*l3 - c; int no = (oc0 == oc1) ? 1 : 2;
        for (int mi = 0; mi < nm; mi++)
          for (int ni = 0; ni < nn; ni++)
            for (int oi = 0; oi < no; oi++){
              int m = mi ? mc1 : mc0;
              int n = ni ? nc1 : nc0;
              int o = oi ? oc1 : oc0;
              double cv = C.v[m][n][o];
              if (cv == 0.0) continue;
              CD p = cmul(cmul(conjc(A1.a[a][m]), conjc(A2.a[b][n])), A3.a[c][o]);
              sre += p.re * cv;
              sim += p.im * cv;
            }
        re[a][b][c] = sre; im[a][b][c] = sim;
        if (cabsd(sre) > maxre) maxre = cabsd(sre);
        if (cabsd(sim) > maxim) maxim = cabsd(sim);
      }
  RCG R{};
  bool useRe = (maxre >= maxim);
  for (int a = 0; a < n1; a++)
    for (int b = 0; b < n2; b++)
      for (int c = 0; c < n3; c++)
        R.v[a][b][c] = (float)(useRe ? re[a][b][c] : im[a][b][c]);
  return R;
}

constexpr int imin_(int a, int b){ return a < b ? a : b; }
constexpr int iabs_(int a){ return a < 0 ? -a : a; }

struct TPW { float w[9][9][9]; };

constexpr TPW tp_tensor(){
  TPW W{};
  for (int l1 = 0; l1 <= 2; l1++)
    for (int l2 = 0; l2 <= 2; l2++)
      for (int l3 = iabs_(l1 - l2); l3 <= imin_(l1 + l2, 2); l3++){
        RCG R = real_cg(l1, l2, l3);
        for (int a = 0; a < 2*l1 + 1; a++)
          for (int b = 0; b < 2*l2 + 1; b++)
            for (int c = 0; c < 2*l3 + 1; c++)
              W.w[l1*l1 + a][l2*l2 + b][l3*l3 + c] += R.v[a][b][c];
      }
  return W;
}

constexpr TPW TPWC = tp_tensor();

// CG(1,1,2) pre-scaled by sqrt(3/2): for unit y1, |CG112 contraction|^2 = 2/3
// exactly (J=2 carries 2/3 of |v x v|^2; CG rows are orthonormal), so the
// reference's _safe_normalize(y2) is multiplication by the constant sqrt(3/2).
struct RCGS { float v[3][3][5]; };
constexpr RCGS cg112_scaled(){
  RCG c = real_cg(1, 1, 2);
  double sc = csqrt(1.5);
  RCGS r{};
  for (int a = 0; a < 3; a++)
    for (int b = 0; b < 3; b++)
      for (int k = 0; k < 5; k++)
        r.v[a][b][k] = (float)((double)c.v[a][b][k] * sc);
  return r;
}
constexpr RCGS CG112S = cg112_scaled();

} // namespace cg

// ======================= CSR build kernels =======================

__global__ __launch_bounds__(256) void hist_kernel(
    const int* __restrict__ rcv, int* __restrict__ counts, int n_edges)
{
  int e = blockIdx.x * 256 + threadIdx.x;
  if (e < n_edges) atomicAdd(&counts[rcv[e]], 1);
}

// Per-block exclusive scan of 1024 elements; writes per-block exclusive
// prefixes to offs and the block total to bsum[blockIdx].
__global__ __launch_bounds__(1024) void scan_blocks(
    const int* __restrict__ counts, int* __restrict__ offs,
    int* __restrict__ bsum, int n)
{
  const int tid = threadIdx.x;
  const int lane = tid & 63, wv = tid >> 6;
  int i = blockIdx.x * 1024 + tid;
  int v = (i < n) ? counts[i] : 0;
  int x = v;
#pragma unroll
  for (int d = 1; d < 64; d <<= 1){
    int y = __shfl_up(x, d, 64);
    if (lane >= d) x += y;
  }
  __shared__ int wsum[16];
  if (lane == 63) wsum[wv] = x;
  __syncthreads();
  if (tid < 16){
    int s = wsum[tid];
    int xs = s;
#pragma unroll
    for (int d = 1; d < 16; d <<= 1){
      int y = __shfl_up(xs, d, 16);
      if (tid >= d) xs += y;
    }
    wsum[tid] = xs - s;   // exclusive prefix of wave sums
  }
  __syncthreads();
  if (i < n) offs[i] = wsum[wv] + (x - v);
  if (tid == 1023) bsum[blockIdx.x] = wsum[15] + x;  // block total
}

// Single-block exclusive scan of the (<=1024) block totals, in place.
// Also writes the grand total to bsum[nb].
__global__ __launch_bounds__(1024) void scan_tops(int* __restrict__ bsum, int nb)
{
  const int tid = threadIdx.x;
  const int lane = tid & 63, wv = tid >> 6;
  int v = (tid < nb) ? bsum[tid] : 0;
  int x = v;
#pragma unroll
  for (int d = 1; d < 64; d <<= 1){
    int y = __shfl_up(x, d, 64);
    if (lane >= d) x += y;
  }
  __shared__ int wsum[16];
  if (lane == 63) wsum[wv] = x;
  __syncthreads();
  if (tid < 16){
    int s = wsum[tid];
    int xs = s;
#pragma unroll
    for (int d = 1; d < 16; d <<= 1){
      int y = __shfl_up(xs, d, 16);
      if (tid >= d) xs += y;
    }
    wsum[tid] = xs - s;
  }
  __syncthreads();
  if (tid == nb - 1) bsum[nb] = wsum[wv] + x;          // grand total
  if (tid < nb)      bsum[tid] = wsum[wv] + (x - v);   // exclusive
}

// offs[i] += block base; cursor[i] = offs[i] (fused copy); offs[n] = total.
// NOTE: counts is NOT an argument (round-6 version aliased counts/cursor
// under __restrict__ -> UB -> OOB gather -> device fault).
__global__ __launch_bounds__(1024) void scan_add(
    int* __restrict__ offs, const int* __restrict__ bsum,
    int* __restrict__ cursor, int n, int nb)
{
  int i = blockIdx.x * 1024 + threadIdx.x;
  if (i < n){
    int o = offs[i] + bsum[blockIdx.x];
    offs[i] = o;
    cursor[i] = o;
  } else if (i == n){
    offs[n] = bsum[nb];  // grand total
  }
}

// Scatter sender ids into receiver-sorted order.
__global__ __launch_bounds__(256) void fill_kernel(
    const int* __restrict__ snd, const int* __restrict__ rcv,
    int* __restrict__ cursor, int* __restrict__ sorted, int n_edges)
{
  int e = blockIdx.x * 256 + threadIdx.x;
  if (e >= n_edges) return;
  int p = atomicAdd(&cursor[rcv[e]], 1);
  sorted[p] = snd[e];
}

// ======================= gather + fused dense =======================
// One WAVE per node. lane = (q,c): c = lane&15 channel, q = lane>>4 edge
// slice. Each lane walks edges idx = b0+q, b0+q+4, ... for its channel;
// cross-q reduction via 2 shfl_xor at the end. No atomics, no divergence
// across nodes within a wave.
__global__ __launch_bounds__(256) void gather_nodes(
    const float* __restrict__ pos,
    const float* __restrict__ nf,
    const float* __restrict__ dw,
    const float* __restrict__ db,
    const int*   __restrict__ offs,
    const int*   __restrict__ sorted,
    float*       __restrict__ out,
    int n_nodes)
{
  int n = (blockIdx.x * 256 + threadIdx.x) >> 6;   // node = global wave id
  if (n >= n_nodes) return;                         // wave-uniform exit
  int lane = threadIdx.x & 63;
  int c = lane & 15;
  int q = lane >> 4;

  float prx = pos[3*n + 0], pry = pos[3*n + 1], prz = pos[3*n + 2];
  int b0 = offs[n], b1 = offs[n + 1];

  float agg[9] = {0.f,0.f,0.f,0.f,0.f,0.f,0.f,0.f,0.f};

  for (int idx = b0 + q; idx < b1; idx += 4){
    int s = sorted[idx];

    float dx = prx - pos[3*s + 0];
    float dy = pry - pos[3*s + 1];
    float dz = prz - pos[3*s + 2];
    float inv = rsqrtf(dx*dx + dy*dy + dz*dz + 1e-12f);

    float y1[3] = { dy*inv, dz*inv, dx*inv };  // (y,z,x)

    float sh[9];
    sh[0] = 1.0f; sh[1] = y1[0]; sh[2] = y1[1]; sh[3] = y1[2];

    // l=2 block: pre-scaled CG112 (constant renormalization folded in)
    float y2[5] = {0.f,0.f,0.f,0.f,0.f};
#pragma unroll
    for (int a = 0; a < 3; a++)
#pragma unroll
      for (int b = 0; b < 3; b++)
#pragma unroll
        for (int k = 0; k < 5; k++)
          if (cg::CG112S.v[a][b][k] != 0.0f)
            y2[k] += y1[a] * y1[b] * cg::CG112S.v[a][b][k];
#pragma unroll
    for (int k = 0; k < 5; k++) sh[4 + k] = y2[k];

    const float* xp = nf + ((size_t)s * NCH + c) * DIRR;
    float x[9];
#pragma unroll
    for (int i = 0; i < 9; i++) x[i] = xp[i];

#pragma unroll
    for (int i = 0; i < 9; i++){
#pragma unroll
      for (int j = 0; j < 9; j++){
#pragma unroll
        for (int k = 0; k < 9; k++){
          if (cg::TPWC.w[i][j][k] != 0.0f)
            agg[k] += (x[i] * sh[j]) * cg::TPWC.w[i][j][k];
        }
      }
    }
  }

  // reduce the 4 edge-slices (lanes differing in bits 4-5)
#pragma unroll
  for (int k = 0; k < 9; k++){
    agg[k] += __shfl_xor(agg[k], 16, 64);
    agg[k] += __shfl_xor(agg[k], 32, 64);
  }

  // fused dense: o = agg @ dw + db (all lanes compute; q==0 lanes store)
  float ov[9];
#pragma unroll
  for (int k = 0; k < 9; k++){
    float v = db[k];
#pragma unroll
    for (int i = 0; i < 9; i++) v += agg[i] * dw[i*9 + k];
    ov[k] = v;
  }
  if (q == 0){
    float* op = out + ((size_t)n * NCH + c) * DIRR;
#pragma unroll
    for (int k = 0; k < 9; k++) op[k] = ov[k];
  }
}

extern "C" void kernel_launch(void* const* d_in, const int* in_sizes, int n_in,
                              void* d_out, int out_size, void* d_ws, size_t ws_size,
                              hipStream_t stream)
{
  const float* pos = (const float*)d_in[0];
  const float* nf  = (const float*)d_in[1];
  const float* dw  = (const float*)d_in[2];
  const float* db  = (const float*)d_in[3];
  const int*   snd = (const int*)d_in[4];
  const int*   rcv = (const int*)d_in[5];
  float* out = (float*)d_out;

  int n_edges = in_sizes[4];
  int n_nodes = in_sizes[0] / 3;
  int nb = (n_nodes + 1023) / 1024;

  // ws layout (ints): offs[n+1] | counts/cursor[n] | sorted[E] | bsum[nb+1]
  int* offs   = (int*)d_ws;
  int* cursor = offs + (n_nodes + 1);
  int* sorted = cursor + n_nodes;
  int* bsum   = sorted + n_edges;

  hipMemsetAsync(cursor, 0, (size_t)n_nodes * sizeof(int), stream);

  hist_kernel<<<dim3((n_edges + 255) / 256), dim3(256), 0, stream>>>(rcv, cursor, n_edges);
  scan_blocks<<<dim3(nb), dim3(1024), 0, stream>>>(cursor, offs, bsum, n_nodes);
  scan_tops<<<dim3(1), dim3(1024), 0, stream>>>(bsum, nb);
  scan_add<<<dim3((n_nodes + 1 + 1023) / 1024), dim3(1024), 0, stream>>>(offs, bsum, cursor, n_nodes, nb);
  fill_kernel<<<dim3((n_edges + 255) / 256), dim3(256), 0, stream>>>(snd, rcv, cursor, sorted, n_edges);

  int blocks = (n_nodes + 3) / 4;  // 4 waves (=4 nodes) per 256-thread block
  gather_nodes<<<dim3(blocks), dim3(256), 0, stream>>>(
      pos, nf, dw, db, offs, sorted, out, n_nodes);
}